// Round 27
// baseline (44.305 us; speedup 1.0000x reference)
//
#include <hip/hip_runtime.h>
#include <hip/hip_fp16.h>
#include <stdint.h>

// Problem constants (match reference)
#define BB 16384
#define SS 20
#define DD 128
#define VV 12
#define EPSV 1e-5f
// eps adjusted for the exp2-folded epilogue: eps / ln(2)^2
#define EPSV2 2.081361e-5f

// R27 = R26 (best: 43.6 us) with ONE change: the 4 ds_bpermute/t neighbor
// exchanges become v_mov_b32_dpp wave shifts (VALU, ~2cyc, no lgkmcnt):
//   left neighbor  (lane i <- i-1): DPP wave_shr1 (0x138)
//   right neighbor (lane i <- i+1): DPP wave_shl1 (0x130)
// bound_ctrl zero-fills the wave edge; the half-wave row boundary (lane 32's
// left = lane 31 of the other row, and vice versa) is already handled by the
// existing mL/mR cndmasks (il==0 / il==31), so masking logic is unchanged.
// Removes ALL DS ops from the main loop (80/wave -> 0) and the per-t
// lgkmcnt stall; frees the la/ra address VGPRs.
// NO launch-bounds min-waves arg. Tripwires: absmax>1.8e-2 (DPP semantics),
// VGPR>64. If null (>=43.3): declare practical plateau.

#define DPP_WAVE_SHL1 0x130
#define DPP_WAVE_SHR1 0x138

static __device__ __forceinline__ uint32_t dpp_from_left(uint32_t v) {
    // lane i receives lane i-1's value; lane 0 -> 0 (bound_ctrl)
    return (uint32_t)__builtin_amdgcn_mov_dpp((int)v, DPP_WAVE_SHR1, 0xf, 0xf, true);
}
static __device__ __forceinline__ uint32_t dpp_from_right(uint32_t v) {
    // lane i receives lane i+1's value; lane 63 -> 0 (bound_ctrl)
    return (uint32_t)__builtin_amdgcn_mov_dpp((int)v, DPP_WAVE_SHL1, 0xf, 0xf, true);
}

static __device__ __forceinline__ uint32_t pk16(float a, float b) {
    return __builtin_bit_cast(uint32_t, __builtin_amdgcn_cvt_pkrtz(a, b));
}
static __device__ __forceinline__ __half2 H2(uint32_t u) {
    return __builtin_bit_cast(__half2, u);
}
static __device__ __forceinline__ uint32_t U32(__half2 h) {
    return __builtin_bit_cast(uint32_t, h);
}

// ---- prep layout in ws ----
// [0   .. 399]  : gate broadcast pairs gwb[t*20+s] = (-c*w[t][s]*pw[s]) x2
// [400 .. 719]  : 20 records x 16 dwords:
//    +0..7 : conv {wc0,wb0,wa0,cw,wa2,wb2,wc2}*pw[t] (broadcast) + bias
//    +8    : (-c*gate_b[t]) pair   (c = log2 e)
//    +9    : (pl, pl), pl = post_w[t]*logit_w[t]
//    +10   : (logit_w[t], logit_w[t])
// [720 .. 1487] : embpk[v*64 + p] = (emb[v][2p], emb[v][2p+1]) f16 pair
__global__ void pack_w_kernel(const float* __restrict__ gate_w,
                              const float* __restrict__ w0, const float* __restrict__ b0,
                              const float* __restrict__ w1, const float* __restrict__ b1,
                              const float* __restrict__ w2, const float* __restrict__ b2,
                              const float* __restrict__ gate_b,
                              const float* __restrict__ post_w,
                              const float* __restrict__ logit_w,
                              const float* __restrict__ pre_w,
                              const float* __restrict__ emb,
                              uint32_t*    __restrict__ ws) {
    const float nc = -1.4426950408889634f;   // -log2(e)
    const int i = threadIdx.x;               // single block of 512
    if (i < SS * SS) {
        const int t = i / SS, s = i % SS;
        const float v = nc * gate_w[t * SS + s] * pre_w[s];
        ws[i] = pk16(v, v);
    }
    if (i < SS) {
        const float pw = pre_w[i];           // conv row i: all taps share s=i
        const float wa0 = w0[i*3+0]*pw, wam = w0[i*3+1]*pw, wa2 = w0[i*3+2]*pw;
        const float wb0 = w1[i*3+0]*pw, wbm = w1[i*3+1]*pw, wb2 = w1[i*3+2]*pw;
        const float wc0 = w2[i*3+0]*pw, wcm = w2[i*3+1]*pw, wc2 = w2[i*3+2]*pw;
        const float cw   = wam + wbm + wcm;
        const float bias = b0[i] + b1[i] + b2[i];   // NOT scaled by pw
        const float gbv  = nc * gate_b[i];
        const float pl   = post_w[i] * logit_w[i];
        const float lw   = logit_w[i];
        uint32_t* o = ws + SS * SS + i * 16;
        o[0] = pk16(wc0, wc0);  o[1] = pk16(wb0, wb0);
        o[2] = pk16(wa0, wa0);  o[3] = pk16(cw,  cw);
        o[4] = pk16(wa2, wa2);  o[5] = pk16(wb2, wb2);
        o[6] = pk16(wc2, wc2);  o[7] = pk16(bias, bias);
        o[8] = pk16(gbv, gbv);  o[9] = pk16(pl, pl);
        o[10] = pk16(lw, lw);
        o[11] = 0u; o[12] = 0u; o[13] = 0u; o[14] = 0u; o[15] = 0u;
    }
    // emb -> packed f16 d-pairs: 12*64 = 768 entries
    for (int k = i; k < VV * (DD / 2); k += 512) {
        const int v = k >> 6, p = k & 63;
        ws[720 + k] = pk16(emb[v * DD + 2*p], emb[v * DD + 2*p + 1]);
    }
}

__global__ __launch_bounds__(256) void fused_mdt_kernel(
    const int*      __restrict__ tokens,   // [B,S]
    const uint32_t* __restrict__ wpk,      // packed weights + emb (from prep)
    float*          __restrict__ out)      // [B,1,D] -> flat [B*D]
{
    const int tid  = threadIdx.x;
    const int lane = tid & 63;             // lane within wave
    const int il   = lane & 31;            // lane within row
    const int b    = blockIdx.x * 8 + (tid >> 5);   // one row per half-wave
    const int d0   = il << 2;

    // edge masks; they also fix the half-wave boundary lanes (32's left /
    // 31's right read the other row via DPP; both are il==0/31 -> masked)
    const bool mL = (il == 0);
    const bool mR = (il == 31);

    const int4* t4 = reinterpret_cast<const int4*>(tokens + b * SS);
    const uint32_t* embp = wpk + 720;      // [12][64] packed d-pairs

    // ---- f16 prologue: 8B load/s, packed ms stats, packed a1 ----
    uint32_t X0[SS], X1[SS];
    __half2 msA = H2(0u), msB = H2(0u), a1pkA = H2(0u), a1pkB = H2(0u);
    #pragma unroll
    for (int i = 0; i < 5; ++i) {
        const int4 tv = t4[i];
        const int tg[4] = {tv.x, tv.y, tv.z, tv.w};
        #pragma unroll
        for (int j = 0; j < 4; ++j) {
            const int s = 4*i + j;
            const uint2 xp = *reinterpret_cast<const uint2*>(embp + tg[j] * 64 + (il << 1));
            X0[s] = xp.x;
            X1[s] = xp.y;
            msA = __hfma2(H2(xp.x), H2(xp.x), msA);
            msB = __hfma2(H2(xp.y), H2(xp.y), msB);
            const __half2 lwpk = H2(wpk[SS * SS + s * 16 + 10]);
            a1pkA = __hfma2(H2(xp.x), lwpk, a1pkA);
            a1pkB = __hfma2(H2(xp.y), lwpk, a1pkB);
        }
    }
    const float r0 = rsqrtf(__low2float(msA)  * (1.f/SS) + EPSV);
    const float r1 = rsqrtf(__high2float(msA) * (1.f/SS) + EPSV);
    const float r2 = rsqrtf(__low2float(msB)  * (1.f/SS) + EPSV);
    const float r3 = rsqrtf(__high2float(msB) * (1.f/SS) + EPSV);

    // rescale packed regs (pre_w folded into weight tables at pack time)
    const __half2 rpA = H2(pk16(r0, r1));
    const __half2 rpB = H2(pk16(r2, r3));
    #pragma unroll
    for (int s = 0; s < SS; ++s) {
        X0[s] = U32(__hmul2(H2(X0[s]), rpA));
        X1[s] = U32(__hmul2(H2(X1[s]), rpB));
    }

    // ---- main loop over t: DPP neighbor exchange + packed conv/gate/SiLU ----
    const __half2 one = __float2half2_rn(1.f);
    __half2 m2pkA = H2(0u), m2pkB = H2(0u), acpkA = H2(0u), acpkB = H2(0u);
    #pragma unroll
    for (int t = 0; t < SS; ++t) {
        uint32_t LX0 = dpp_from_left(X0[t]);    // (d0-4, d0-3)
        uint32_t LX1 = dpp_from_left(X1[t]);    // (d0-2, d0-1)
        uint32_t RX0 = dpp_from_right(X0[t]);   // (d0+4, d0+5)
        uint32_t RX1 = dpp_from_right(X1[t]);   // (d0+6, d0+7)
        LX0 = mL ? 0u : LX0;  LX1 = mL ? 0u : LX1;
        RX0 = mR ? 0u : RX0;  RX1 = mR ? 0u : RX1;
        const uint32_t Dm1 = __builtin_amdgcn_alignbit(X0[t], LX1, 16);  // (d0-1, d0)
        const uint32_t Dc  = __builtin_amdgcn_alignbit(X1[t], X0[t], 16);// (d0+1, d0+2)
        const uint32_t Dp1 = __builtin_amdgcn_alignbit(RX0, X1[t], 16);  // (d0+3, d0+4)

        // conv: 14 packed fma, weights broadcast-packed (pw pre-folded)
        const uint32_t* rec = wpk + SS * SS + t * 16;
        __half2 xdA = H2(rec[7]);                    // chunk (d0, d0+1)
        xdA = __hfma2(H2(rec[0]), H2(LX0),   xdA);   // d-4
        xdA = __hfma2(H2(rec[1]), H2(LX1),   xdA);   // d-2
        xdA = __hfma2(H2(rec[2]), H2(Dm1),   xdA);   // d-1
        xdA = __hfma2(H2(rec[3]), H2(X0[t]), xdA);   // center (merged)
        xdA = __hfma2(H2(rec[4]), H2(Dc),    xdA);   // d+1
        xdA = __hfma2(H2(rec[5]), H2(X1[t]), xdA);   // d+2
        xdA = __hfma2(H2(rec[6]), H2(RX0),   xdA);   // d+4
        __half2 xdB = H2(rec[7]);                    // chunk (d0+2, d0+3)
        xdB = __hfma2(H2(rec[0]), H2(LX1),   xdB);   // d-4
        xdB = __hfma2(H2(rec[1]), H2(X0[t]), xdB);   // d-2
        xdB = __hfma2(H2(rec[2]), H2(Dc),    xdB);   // d-1
        xdB = __hfma2(H2(rec[3]), H2(X1[t]), xdB);   // center
        xdB = __hfma2(H2(rec[4]), H2(Dp1),   xdB);   // d+1
        xdB = __hfma2(H2(rec[5]), H2(RX0),   xdB);   // d+2
        xdB = __hfma2(H2(rec[6]), H2(RX1),   xdB);   // d+4

        // gate row t: accumulates gl = -log2e*g (weights pre-scaled, pw folded)
        __half2 gaA = H2(rec[8]), gbA = H2(0u);
        __half2 gaB = H2(rec[8]), gbB = H2(0u);
        #pragma unroll
        for (int q = 0; q < SS / 2; ++q) {
            const __half2 hw0 = H2(wpk[t * SS + 2*q    ]);
            const __half2 hw1 = H2(wpk[t * SS + 2*q + 1]);
            gaA = __hfma2(hw0, H2(X0[2*q    ]), gaA);
            gbA = __hfma2(hw1, H2(X0[2*q + 1]), gbA);
            gaB = __hfma2(hw0, H2(X1[2*q    ]), gaB);
            gbB = __hfma2(hw1, H2(X1[2*q + 1]), gbB);
        }
        const __half2 glA = __hadd2(gaA, gbA);
        const __half2 glB = __hadd2(gaB, gbB);

        // SiLU via exp2: sigma = rcp(1 + 2^gl); h' = xd * gl * sigma
        const __half2 eA  = h2exp2(glA);
        const __half2 eB  = h2exp2(glB);
        const __half2 rcA = h2rcp(__hadd2(one, eA));
        const __half2 rcB = h2rcp(__hadd2(one, eB));
        const __half2 hhA = __hmul2(xdA, __hmul2(glA, rcA));
        const __half2 hhB = __hmul2(xdB, __hmul2(glB, rcB));

        // packed post-RMS accumulation (h' carries -log2e; folded exactly)
        const __half2 plpk = H2(rec[9]);
        m2pkA = __hfma2(hhA, hhA, m2pkA);
        m2pkB = __hfma2(hhB, hhB, m2pkB);
        acpkA = __hfma2(hhA, plpk, acpkA);
        acpkB = __hfma2(hhB, plpk, acpkB);
    }

    // out = a1 - rsqrt(M'/20 + eps/ln2^2) * ac'   (exact folding)
    const float q0 = rsqrtf(__low2float(m2pkA)  * (1.f/SS) + EPSV2);
    const float q1 = rsqrtf(__high2float(m2pkA) * (1.f/SS) + EPSV2);
    const float q2 = rsqrtf(__low2float(m2pkB)  * (1.f/SS) + EPSV2);
    const float q3 = rsqrtf(__high2float(m2pkB) * (1.f/SS) + EPSV2);

    float4 res;
    res.x = __low2float(a1pkA)  - q0 * __low2float(acpkA);
    res.y = __high2float(a1pkA) - q1 * __high2float(acpkA);
    res.z = __low2float(a1pkB)  - q2 * __low2float(acpkB);
    res.w = __high2float(a1pkB) - q3 * __high2float(acpkB);
    *reinterpret_cast<float4*>(out + b * DD + d0) = res;
}

extern "C" void kernel_launch(void* const* d_in, const int* in_sizes, int n_in,
                              void* d_out, int out_size, void* d_ws, size_t ws_size,
                              hipStream_t stream) {
    const int*   tokens  = (const int*)  d_in[0];
    // d_in[1] = number_log — unused by the reference
    const float* emb     = (const float*)d_in[2];
    const float* pre_w   = (const float*)d_in[3];
    const float* w0      = (const float*)d_in[4];
    const float* b0      = (const float*)d_in[5];
    const float* w1      = (const float*)d_in[6];
    const float* b1      = (const float*)d_in[7];
    const float* w2      = (const float*)d_in[8];
    const float* b2      = (const float*)d_in[9];
    const float* gate_w  = (const float*)d_in[10];
    const float* gate_b  = (const float*)d_in[11];
    const float* post_w  = (const float*)d_in[12];
    const float* logit_w = (const float*)d_in[13];
    float*       out     = (float*)d_out;
    uint32_t*    ws      = (uint32_t*)d_ws;

    hipLaunchKernelGGL(pack_w_kernel, dim3(1), dim3(512), 0, stream,
                       gate_w, w0, b0, w1, b1, w2, b2,
                       gate_b, post_w, logit_w, pre_w, emb, ws);

    dim3 grid(BB / 8);   // 8 rows (4 waves x 2) per 256-thread block
    dim3 block(256);
    hipLaunchKernelGGL(fused_mdt_kernel, grid, block, 0, stream,
                       tokens, (const uint32_t*)ws, out);
}

// Round 28
// 43.510 us; speedup vs baseline: 1.0183x; 1.0183x over previous
//
#include <hip/hip_runtime.h>
#include <hip/hip_fp16.h>
#include <stdint.h>

// Problem constants (match reference)
#define BB 16384
#define SS 20
#define DD 128
#define VV 12
#define EPSV 1e-5f
// eps adjusted for the exp2-folded epilogue: eps / ln(2)^2
#define EPSV2 2.081361e-5f

// R28 = R26 verbatim (best: 43.6 us) — final revert after R27's DPP variant
// proved null-to-negative (moved neighbor exchange from idle DS pipe into
// the VALU stream). This is the session's practical plateau:
//   not memory-bound (2.9% HBM), not pipe-bound (~49% of the 19.3 us VALU
//   issue floor); dependency-latency-bound at max natural residency with
//   all structural levers tested (geometry, residency, pipelining, weight
//   streams, DS/DPP, instruction diet). Gate (40 pk_fma/t) is the
//   irreducible half of the stream; MFMA redistribution costs exceed its
//   savings at S=20.
// Structure: 1 wave = 2 rows, 4 d/lane as 2 packed f16x2 regs/s (X0,X1);
// f16 prologue (pre-packed emb table, packed ms stats, packed a1);
// rescale by packed rsqrt pairs (pre_w folded into weight tables);
// main loop: 4 bperm + 3 alignbit + 14 conv pk_fma + 40 gate pk_fma +
// exp2-folded SiLU (weights pre-scaled by -log2e; -1/ln2 folded exactly
// into the epilogue: out = a1 - rsqrt(M'/20 + eps/ln2^2)*ac').

#define BPERMU(addr, v) ((uint32_t)__builtin_amdgcn_ds_bpermute((addr), (int)(v)))

static __device__ __forceinline__ uint32_t pk16(float a, float b) {
    return __builtin_bit_cast(uint32_t, __builtin_amdgcn_cvt_pkrtz(a, b));
}
static __device__ __forceinline__ __half2 H2(uint32_t u) {
    return __builtin_bit_cast(__half2, u);
}
static __device__ __forceinline__ uint32_t U32(__half2 h) {
    return __builtin_bit_cast(uint32_t, h);
}

// ---- prep layout in ws ----
// [0   .. 399]  : gate broadcast pairs gwb[t*20+s] = (-c*w[t][s]*pw[s]) x2
// [400 .. 719]  : 20 records x 16 dwords:
//    +0..7 : conv {wc0,wb0,wa0,cw,wa2,wb2,wc2}*pw[t] (broadcast) + bias
//    +8    : (-c*gate_b[t]) pair   (c = log2 e)
//    +9    : (pl, pl), pl = post_w[t]*logit_w[t]
//    +10   : (logit_w[t], logit_w[t])
// [720 .. 1487] : embpk[v*64 + p] = (emb[v][2p], emb[v][2p+1]) f16 pair
__global__ void pack_w_kernel(const float* __restrict__ gate_w,
                              const float* __restrict__ w0, const float* __restrict__ b0,
                              const float* __restrict__ w1, const float* __restrict__ b1,
                              const float* __restrict__ w2, const float* __restrict__ b2,
                              const float* __restrict__ gate_b,
                              const float* __restrict__ post_w,
                              const float* __restrict__ logit_w,
                              const float* __restrict__ pre_w,
                              const float* __restrict__ emb,
                              uint32_t*    __restrict__ ws) {
    const float nc = -1.4426950408889634f;   // -log2(e)
    const int i = threadIdx.x;               // single block of 512
    if (i < SS * SS) {
        const int t = i / SS, s = i % SS;
        const float v = nc * gate_w[t * SS + s] * pre_w[s];
        ws[i] = pk16(v, v);
    }
    if (i < SS) {
        const float pw = pre_w[i];           // conv row i: all taps share s=i
        const float wa0 = w0[i*3+0]*pw, wam = w0[i*3+1]*pw, wa2 = w0[i*3+2]*pw;
        const float wb0 = w1[i*3+0]*pw, wbm = w1[i*3+1]*pw, wb2 = w1[i*3+2]*pw;
        const float wc0 = w2[i*3+0]*pw, wcm = w2[i*3+1]*pw, wc2 = w2[i*3+2]*pw;
        const float cw   = wam + wbm + wcm;
        const float bias = b0[i] + b1[i] + b2[i];   // NOT scaled by pw
        const float gbv  = nc * gate_b[i];
        const float pl   = post_w[i] * logit_w[i];
        const float lw   = logit_w[i];
        uint32_t* o = ws + SS * SS + i * 16;
        o[0] = pk16(wc0, wc0);  o[1] = pk16(wb0, wb0);
        o[2] = pk16(wa0, wa0);  o[3] = pk16(cw,  cw);
        o[4] = pk16(wa2, wa2);  o[5] = pk16(wb2, wb2);
        o[6] = pk16(wc2, wc2);  o[7] = pk16(bias, bias);
        o[8] = pk16(gbv, gbv);  o[9] = pk16(pl, pl);
        o[10] = pk16(lw, lw);
        o[11] = 0u; o[12] = 0u; o[13] = 0u; o[14] = 0u; o[15] = 0u;
    }
    // emb -> packed f16 d-pairs: 12*64 = 768 entries
    for (int k = i; k < VV * (DD / 2); k += 512) {
        const int v = k >> 6, p = k & 63;
        ws[720 + k] = pk16(emb[v * DD + 2*p], emb[v * DD + 2*p + 1]);
    }
}

__global__ __launch_bounds__(256) void fused_mdt_kernel(
    const int*      __restrict__ tokens,   // [B,S]
    const uint32_t* __restrict__ wpk,      // packed weights + emb (from prep)
    float*          __restrict__ out)      // [B,1,D] -> flat [B*D]
{
    const int tid  = threadIdx.x;
    const int lane = tid & 63;             // lane within wave
    const int il   = lane & 31;            // lane within row
    const int b    = blockIdx.x * 8 + (tid >> 5);   // one row per half-wave
    const int d0   = il << 2;

    // edge masks; half-wave boundary == il==0/31 masked case (no cross-row)
    const bool mL = (il == 0);
    const bool mR = (il == 31);
    const int  la = (lane - 1) << 2;
    const int  ra = (lane + 1) << 2;

    const int4* t4 = reinterpret_cast<const int4*>(tokens + b * SS);
    const uint32_t* embp = wpk + 720;      // [12][64] packed d-pairs

    // ---- f16 prologue: 8B load/s, packed ms stats, packed a1 ----
    uint32_t X0[SS], X1[SS];
    __half2 msA = H2(0u), msB = H2(0u), a1pkA = H2(0u), a1pkB = H2(0u);
    #pragma unroll
    for (int i = 0; i < 5; ++i) {
        const int4 tv = t4[i];
        const int tg[4] = {tv.x, tv.y, tv.z, tv.w};
        #pragma unroll
        for (int j = 0; j < 4; ++j) {
            const int s = 4*i + j;
            const uint2 xp = *reinterpret_cast<const uint2*>(embp + tg[j] * 64 + (il << 1));
            X0[s] = xp.x;
            X1[s] = xp.y;
            msA = __hfma2(H2(xp.x), H2(xp.x), msA);
            msB = __hfma2(H2(xp.y), H2(xp.y), msB);
            const __half2 lwpk = H2(wpk[SS * SS + s * 16 + 10]);
            a1pkA = __hfma2(H2(xp.x), lwpk, a1pkA);
            a1pkB = __hfma2(H2(xp.y), lwpk, a1pkB);
        }
    }
    const float r0 = rsqrtf(__low2float(msA)  * (1.f/SS) + EPSV);
    const float r1 = rsqrtf(__high2float(msA) * (1.f/SS) + EPSV);
    const float r2 = rsqrtf(__low2float(msB)  * (1.f/SS) + EPSV);
    const float r3 = rsqrtf(__high2float(msB) * (1.f/SS) + EPSV);

    // rescale packed regs (pre_w folded into weight tables at pack time)
    const __half2 rpA = H2(pk16(r0, r1));
    const __half2 rpB = H2(pk16(r2, r3));
    #pragma unroll
    for (int s = 0; s < SS; ++s) {
        X0[s] = U32(__hmul2(H2(X0[s]), rpA));
        X1[s] = U32(__hmul2(H2(X1[s]), rpB));
    }

    // ---- main loop over t: 4 bperm + 3 splice + packed conv/gate/SiLU ----
    const __half2 one = __float2half2_rn(1.f);
    __half2 m2pkA = H2(0u), m2pkB = H2(0u), acpkA = H2(0u), acpkB = H2(0u);
    #pragma unroll
    for (int t = 0; t < SS; ++t) {
        uint32_t LX0 = BPERMU(la, X0[t]);   // (d0-4, d0-3)
        uint32_t LX1 = BPERMU(la, X1[t]);   // (d0-2, d0-1)
        uint32_t RX0 = BPERMU(ra, X0[t]);   // (d0+4, d0+5)
        uint32_t RX1 = BPERMU(ra, X1[t]);   // (d0+6, d0+7)
        LX0 = mL ? 0u : LX0;  LX1 = mL ? 0u : LX1;
        RX0 = mR ? 0u : RX0;  RX1 = mR ? 0u : RX1;
        const uint32_t Dm1 = __builtin_amdgcn_alignbit(X0[t], LX1, 16);  // (d0-1, d0)
        const uint32_t Dc  = __builtin_amdgcn_alignbit(X1[t], X0[t], 16);// (d0+1, d0+2)
        const uint32_t Dp1 = __builtin_amdgcn_alignbit(RX0, X1[t], 16);  // (d0+3, d0+4)

        // conv: 14 packed fma, weights broadcast-packed (pw pre-folded)
        const uint32_t* rec = wpk + SS * SS + t * 16;
        __half2 xdA = H2(rec[7]);                    // chunk (d0, d0+1)
        xdA = __hfma2(H2(rec[0]), H2(LX0),   xdA);   // d-4
        xdA = __hfma2(H2(rec[1]), H2(LX1),   xdA);   // d-2
        xdA = __hfma2(H2(rec[2]), H2(Dm1),   xdA);   // d-1
        xdA = __hfma2(H2(rec[3]), H2(X0[t]), xdA);   // center (merged)
        xdA = __hfma2(H2(rec[4]), H2(Dc),    xdA);   // d+1
        xdA = __hfma2(H2(rec[5]), H2(X1[t]), xdA);   // d+2
        xdA = __hfma2(H2(rec[6]), H2(RX0),   xdA);   // d+4
        __half2 xdB = H2(rec[7]);                    // chunk (d0+2, d0+3)
        xdB = __hfma2(H2(rec[0]), H2(LX1),   xdB);   // d-4
        xdB = __hfma2(H2(rec[1]), H2(X0[t]), xdB);   // d-2
        xdB = __hfma2(H2(rec[2]), H2(Dc),    xdB);   // d-1
        xdB = __hfma2(H2(rec[3]), H2(X1[t]), xdB);   // center
        xdB = __hfma2(H2(rec[4]), H2(Dp1),   xdB);   // d+1
        xdB = __hfma2(H2(rec[5]), H2(RX0),   xdB);   // d+2
        xdB = __hfma2(H2(rec[6]), H2(RX1),   xdB);   // d+4

        // gate row t: accumulates gl = -log2e*g (weights pre-scaled, pw folded)
        __half2 gaA = H2(rec[8]), gbA = H2(0u);
        __half2 gaB = H2(rec[8]), gbB = H2(0u);
        #pragma unroll
        for (int q = 0; q < SS / 2; ++q) {
            const __half2 hw0 = H2(wpk[t * SS + 2*q    ]);
            const __half2 hw1 = H2(wpk[t * SS + 2*q + 1]);
            gaA = __hfma2(hw0, H2(X0[2*q    ]), gaA);
            gbA = __hfma2(hw1, H2(X0[2*q + 1]), gbA);
            gaB = __hfma2(hw0, H2(X1[2*q    ]), gaB);
            gbB = __hfma2(hw1, H2(X1[2*q + 1]), gbB);
        }
        const __half2 glA = __hadd2(gaA, gbA);
        const __half2 glB = __hadd2(gaB, gbB);

        // SiLU via exp2: sigma = rcp(1 + 2^gl); h' = xd * gl * sigma
        const __half2 eA  = h2exp2(glA);
        const __half2 eB  = h2exp2(glB);
        const __half2 rcA = h2rcp(__hadd2(one, eA));
        const __half2 rcB = h2rcp(__hadd2(one, eB));
        const __half2 hhA = __hmul2(xdA, __hmul2(glA, rcA));
        const __half2 hhB = __hmul2(xdB, __hmul2(glB, rcB));

        // packed post-RMS accumulation (h' carries -log2e; folded exactly)
        const __half2 plpk = H2(rec[9]);
        m2pkA = __hfma2(hhA, hhA, m2pkA);
        m2pkB = __hfma2(hhB, hhB, m2pkB);
        acpkA = __hfma2(hhA, plpk, acpkA);
        acpkB = __hfma2(hhB, plpk, acpkB);
    }

    // out = a1 - rsqrt(M'/20 + eps/ln2^2) * ac'   (exact folding)
    const float q0 = rsqrtf(__low2float(m2pkA)  * (1.f/SS) + EPSV2);
    const float q1 = rsqrtf(__high2float(m2pkA) * (1.f/SS) + EPSV2);
    const float q2 = rsqrtf(__low2float(m2pkB)  * (1.f/SS) + EPSV2);
    const float q3 = rsqrtf(__high2float(m2pkB) * (1.f/SS) + EPSV2);

    float4 res;
    res.x = __low2float(a1pkA)  - q0 * __low2float(acpkA);
    res.y = __high2float(a1pkA) - q1 * __high2float(acpkA);
    res.z = __low2float(a1pkB)  - q2 * __low2float(acpkB);
    res.w = __high2float(a1pkB) - q3 * __high2float(acpkB);
    *reinterpret_cast<float4*>(out + b * DD + d0) = res;
}

extern "C" void kernel_launch(void* const* d_in, const int* in_sizes, int n_in,
                              void* d_out, int out_size, void* d_ws, size_t ws_size,
                              hipStream_t stream) {
    const int*   tokens  = (const int*)  d_in[0];
    // d_in[1] = number_log — unused by the reference
    const float* emb     = (const float*)d_in[2];
    const float* pre_w   = (const float*)d_in[3];
    const float* w0      = (const float*)d_in[4];
    const float* b0      = (const float*)d_in[5];
    const float* w1      = (const float*)d_in[6];
    const float* b1      = (const float*)d_in[7];
    const float* w2      = (const float*)d_in[8];
    const float* b2      = (const float*)d_in[9];
    const float* gate_w  = (const float*)d_in[10];
    const float* gate_b  = (const float*)d_in[11];
    const float* post_w  = (const float*)d_in[12];
    const float* logit_w = (const float*)d_in[13];
    float*       out     = (float*)d_out;
    uint32_t*    ws      = (uint32_t*)d_ws;

    hipLaunchKernelGGL(pack_w_kernel, dim3(1), dim3(512), 0, stream,
                       gate_w, w0, b0, w1, b1, w2, b2,
                       gate_b, post_w, logit_w, pre_w, emb, ws);

    dim3 grid(BB / 8);   // 8 rows (4 waves x 2) per 256-thread block
    dim3 block(256);
    hipLaunchKernelGGL(fused_mdt_kernel, grid, block, 0, stream,
                       tokens, (const uint32_t*)ws, out);
}